// Round 15
// baseline (339.463 us; speedup 1.0000x reference)
//
#include <hip/hip_runtime.h>
#include <math.h>

typedef __bf16 bf16x8 __attribute__((ext_vector_type(8)));
typedef float f32x4 __attribute__((ext_vector_type(4)));
typedef short short8v __attribute__((ext_vector_type(8)));

#define MARGIN 0.01f
#define NCAND 32

#define WAITL  do { asm volatile("s_waitcnt lgkmcnt(0)" ::: "memory"); __builtin_amdgcn_sched_barrier(0); } while (0)
#define WAITV0 do { asm volatile("s_waitcnt vmcnt(0)" ::: "memory"); __builtin_amdgcn_sched_barrier(0); } while (0)
#define BARR   do { __builtin_amdgcn_s_barrier(); __builtin_amdgcn_sched_barrier(0); } while (0)

__device__ __forceinline__ unsigned short f2bf(float f) {
  unsigned u = __float_as_uint(f);
  u += 0x7fffu + ((u >> 16) & 1u);
  return (unsigned short)(u >> 16);
}
__device__ __forceinline__ float tanh_fast(float x) {
  float e = __builtin_amdgcn_exp2f(x * 2.885390081777927f);
  return 1.f - 2.f * __builtin_amdgcn_rcpf(e + 1.f);
}
__device__ __forceinline__ void gl_lds16(const void* g, void* l) {
  __builtin_amdgcn_global_load_lds(
      (const __attribute__((address_space(1))) unsigned int*)g,
      (__attribute__((address_space(3))) unsigned int*)l, 16, 0, 0);
}
// DPP row_shr 16-lane reduce; row sum lands in lane 15 (verified R11).
__device__ __forceinline__ float dpp_row_reduce(float v) {
  int x;
  x = __builtin_amdgcn_update_dpp(0, __builtin_bit_cast(int, v), 0x118, 0xf, 0xf, true);
  v += __builtin_bit_cast(float, x);
  x = __builtin_amdgcn_update_dpp(0, __builtin_bit_cast(int, v), 0x114, 0xf, 0xf, true);
  v += __builtin_bit_cast(float, x);
  x = __builtin_amdgcn_update_dpp(0, __builtin_bit_cast(int, v), 0x112, 0xf, 0xf, true);
  v += __builtin_bit_cast(float, x);
  x = __builtin_amdgcn_update_dpp(0, __builtin_bit_cast(int, v), 0x111, 0xf, 0xf, true);
  v += __builtin_bit_cast(float, x);
  return v;
}

// Fused small prep: blocks [0,512) pack W (bf16, region layout), [512,576) inp.
__global__ __launch_bounds__(256) void prep_small_k(
    const float* __restrict__ x, const float* __restrict__ Wi,
    const float* __restrict__ bi,
    const float* __restrict__ w0, const float* __restrict__ w1,
    const float* __restrict__ w2, const float* __restrict__ w3,
    short* __restrict__ Whi, float* __restrict__ inp) {
  int bid = blockIdx.x;
  if (bid < 512) {
    int gid = bid * 256 + threadIdx.x;   // 131072 chunks of 8
    int c = gid & 3, row = (gid >> 2) & 255, TK = gid >> 10;  // TK = TN*16+KS
    int TN = TK >> 4, KS = TK & 15;
    int n = TN * 256 + row;
    int g = n >> 9, h = n & 511;
    const float* w = (g == 0) ? w0 : (g == 1) ? w1 : (g == 2) ? w2 : w3;
    const float* src = w + (size_t)h * 512 + KS * 32 + c * 8;
    float f[8];
    *(float4*)&f[0] = *(const float4*)(src);
    *(float4*)&f[4] = *(const float4*)(src + 4);
    short8v hv;
    #pragma unroll
    for (int i = 0; i < 8; ++i) hv[i] = (short)f2bf(f[i]);
    *(short8v*)(Whi + (size_t)gid * 8) = hv;
  } else {
    int gid = (bid - 512) * 256 + threadIdx.x;   // 16384
    int b = gid >> 9, h = gid & 511;
    const float* xr = x + b * 512;
    const float* wr = Wi + h * 512;
    float acc = bi[h];
    #pragma unroll 4
    for (int k = 0; k < 512; k += 4) {
      float4 xv = *(const float4*)(xr + k);
      float4 wv = *(const float4*)(wr + k);
      acc += xv.x * wv.x + xv.y * wv.y + xv.z * wv.z + xv.w * wv.w;
    }
    inp[gid] = acc;
  }
}

// Fused GEMM: 256x256 tile, 16 K-tiles BK=32, 8 waves (2x4), per-wave 128x64.
// A staged IN-KERNEL from fp32 ctx (load+cvt+ds_write, no Chi pass); B via
// global_load_lds from packed Whi. 4-slot LDS ring, drain waits, 1 bar/tile.
__global__ __launch_bounds__(512, 2) void gemm_fused_k(
    const float* __restrict__ ctx, const short* __restrict__ Whi,
    const float* __restrict__ inp,
    const float* __restrict__ bc0, const float* __restrict__ bc1,
    const float* __restrict__ bc2, const float* __restrict__ bc3,
    const float* __restrict__ V, float* __restrict__ att) {
  __shared__ __align__(16) short smem[4][2][8192];   // 128 KiB: [ring][A|B]
  __shared__ float sV[256], sPre[256];

  const int t = threadIdx.x;
  int d = blockIdx.x + (blockIdx.y << 3);
  int work = (d & 7) * 256 + (d >> 3);           // XCD-contiguous chunks
  int mt = work >> 3, nt = work & 7;
  int b = mt >> 3;
  int g = nt >> 1, h0 = (nt & 1) * 256;

  if (t < 256) {
    const float* bc = (g == 0) ? bc0 : (g == 1) ? bc1 : (g == 2) ? bc2 : bc3;
    sV[t] = V[h0 + t];
    sPre[t] = inp[b * 512 + h0 + t] + bc[h0 + t];
  }

  const int toff = t * 8;
  // A: fp32 ctx -> bf16 -> ds_write into ring slot (2 passes, 1024 chunks)
  auto stageA = [&](int tile) {
    #pragma unroll
    for (int pass = 0; pass < 2; ++pass) {
      int cc = pass * 512 + t;
      int c = cc & 3, r = cc >> 2;
      int k = tile * 32 + c * 8;
      const float* src = ctx + ((size_t)mt * 256 + r) * 512 + k;
      float f[8];
      *(float4*)&f[0] = *(const float4*)src;
      *(float4*)&f[4] = *(const float4*)(src + 4);
      short8v hv;
      #pragma unroll
      for (int i = 0; i < 8; ++i) hv[i] = (short)f2bf(f[i]);
      *(short8v*)(&smem[tile & 3][0][r * 32 + c * 8]) = hv;
    }
  };
  auto stageB = [&](int tile) {
    const short* gB = Whi + (((size_t)nt * 16 + tile) << 13) + toff;
    short* lB = &smem[tile & 3][1][0];
    gl_lds16(gB,        lB + toff);
    gl_lds16(gB + 4096, lB + toff + 4096);
  };

  f32x4 acc[8][4];
  #pragma unroll
  for (int i = 0; i < 8; ++i)
    #pragma unroll
    for (int j = 0; j < 4; ++j) acc[i][j] = (f32x4){0.f, 0.f, 0.f, 0.f};

  const int lane = t & 63, wid = t >> 6;
  const int wr = wid >> 2, wc = wid & 3;
  const int fr = lane & 15, fq = lane >> 4;
  const int abase = (wr * 128 + fr) * 32 + fq * 8;
  const int bbase = (wc * 64 + fr) * 32 + fq * 8;

  stageA(0); stageB(0);
  WAITV0; WAITL;
  BARR;

  #pragma unroll 4
  for (int tt = 0; tt < 16; ++tt) {
    const short* sa = &smem[tt & 3][0][0];
    const short* sb = &smem[tt & 3][1][0];
    bf16x8 a[8], b0, b1, b2, b3;
    #pragma unroll
    for (int mi = 0; mi < 8; ++mi)
      a[mi] = *(const bf16x8*)(sa + abase + mi * 512);
    b0 = *(const bf16x8*)(sb + bbase);
    b1 = *(const bf16x8*)(sb + bbase + 512);
    b2 = *(const bf16x8*)(sb + bbase + 1024);
    b3 = *(const bf16x8*)(sb + bbase + 1536);
    WAITL;
    __builtin_amdgcn_s_setprio(1);
    #pragma unroll
    for (int mi = 0; mi < 8; ++mi) {
      acc[mi][0] = __builtin_amdgcn_mfma_f32_16x16x32_bf16(a[mi], b0, acc[mi][0], 0, 0, 0);
      acc[mi][1] = __builtin_amdgcn_mfma_f32_16x16x32_bf16(a[mi], b1, acc[mi][1], 0, 0, 0);
    }
    #pragma unroll
    for (int mi = 0; mi < 8; ++mi) {
      acc[mi][2] = __builtin_amdgcn_mfma_f32_16x16x32_bf16(a[mi], b2, acc[mi][2], 0, 0, 0);
      acc[mi][3] = __builtin_amdgcn_mfma_f32_16x16x32_bf16(a[mi], b3, acc[mi][3], 0, 0, 0);
    }
    __builtin_amdgcn_s_setprio(0);
    __builtin_amdgcn_sched_barrier(0);
    if (tt < 15) {
      stageA(tt + 1);          // fp32 loads + cvt + ds_write (slot tt+1)
      stageB(tt + 1);          // gl_lds (slot tt+1)
      WAITV0; WAITL;           // drain gl_lds + ds_writes before barrier
    }
    BARR;
  }

  // epilogue: att[b, g*2048 + s] += sum_n V[h]*tanh(pre[h] + Y[n,s])
  float vV[4], vP[4];
  #pragma unroll
  for (int ni = 0; ni < 4; ++ni) {
    int j = wc * 64 + ni * 16 + fr;
    vV[ni] = sV[j];
    vP[ni] = sPre[j];
  }
  size_t abatt = (size_t)b * 8192 + (size_t)g * 2048;
  #pragma unroll
  for (int mi = 0; mi < 8; ++mi) {
    #pragma unroll
    for (int r = 0; r < 4; ++r) {
      float sum = 0.f;
      #pragma unroll
      for (int ni = 0; ni < 4; ++ni)
        sum += vV[ni] * tanh_fast(vP[ni] + acc[mi][ni][r]);
      sum = dpp_row_reduce(sum);
      if (fr == 15) {
        int s = (mt * 256 + wr * 128 + mi * 16 + fq * 4 + r) & 2047;
        atomicAdd(&att[abatt + s], sum);
      }
    }
  }
}

// Tail: max + denom + candidates, exact fp32 rescore, final outputs.
__global__ __launch_bounds__(1024) void tail_k(const float* __restrict__ att,
    const unsigned char* __restrict__ mask, const float* __restrict__ ctx,
    const float* __restrict__ Wc0, const float* __restrict__ Wc1,
    const float* __restrict__ Wc2, const float* __restrict__ Wc3,
    const float* __restrict__ bc0, const float* __restrict__ bc1,
    const float* __restrict__ bc2, const float* __restrict__ bc3,
    const float* __restrict__ inp, const float* __restrict__ V,
    float* __restrict__ out) {
  int b = blockIdx.x, t = threadIdx.x;
  __shared__ float sred[1024];
  __shared__ float sctx[512];
  __shared__ int scnt;
  __shared__ int scand_j[NCAND];
  __shared__ float scand_a[NCAND];
  __shared__ float sexact[NCAND];

  if (t == 0) scnt = 0;
  float bm = -1e30f;
  for (int j = t; j < 8192; j += 1024) {
    if (mask[b * 2048 + (j & 2047)]) continue;
    bm = fmaxf(bm, att[(size_t)b * 8192 + j]);
  }
  sred[t] = bm;
  __syncthreads();
  for (int s2 = 512; s2 > 0; s2 >>= 1) {
    if (t < s2) sred[t] = fmaxf(sred[t], sred[t + s2]);
    __syncthreads();
  }
  float mx = sred[0];
  float Lref = 10.f * tanhf(mx);
  __syncthreads();
  float se = 0.f;
  for (int j = t; j < 8192; j += 1024) {
    if (mask[b * 2048 + (j & 2047)]) continue;
    float a = att[(size_t)b * 8192 + j];
    se += expf(10.f * tanhf(a) - Lref);
    if (a >= mx - MARGIN) {
      int slot = atomicAdd(&scnt, 1);
      if (slot < NCAND) { scand_j[slot] = j; scand_a[slot] = a; }
    }
  }
  sred[t] = se;
  __syncthreads();
  for (int s2 = 512; s2 > 0; s2 >>= 1) {
    if (t < s2) sred[t] += sred[t + s2];
    __syncthreads();
  }
  float den = sred[0];
  int n = min(scnt, NCAND);
  for (int j = t; j < 2048; j += 1024)
    out[64 + b * 2048 + j] = mask[b * 2048 + j] ? 1.0f : 0.0f;
  for (int i = 0; i < n; ++i) {
    int jj = scand_j[i];
    int g = jj >> 11, s = jj & 2047;
    const float* W  = (g == 0) ? Wc0 : (g == 1) ? Wc1 : (g == 2) ? Wc2 : Wc3;
    const float* bc = (g == 0) ? bc0 : (g == 1) ? bc1 : (g == 2) ? bc2 : bc3;
    const float* cr = ctx + ((size_t)b * 2048 + s) * 512;
    __syncthreads();
    if (t < 512) sctx[t] = cr[t];
    __syncthreads();
    float total = 0.f;
    if (t < 512) {
      const float* wrp = W + (size_t)t * 512;
      float acc = 0.f;
      #pragma unroll 4
      for (int k = 0; k < 512; k += 4) {
        float4 wv = *(const float4*)(wrp + k);
        acc += wv.x * sctx[k] + wv.y * sctx[k + 1] + wv.z * sctx[k + 2] + wv.w * sctx[k + 3];
      }
      total = V[t] * tanhf(inp[b * 512 + t] + bc[t] + acc);
    }
    sred[t] = total;
    __syncthreads();
    for (int s2 = 512; s2 > 0; s2 >>= 1) {
      if (t < s2) sred[t] += sred[t + s2];
      __syncthreads();
    }
    if (t == 0) sexact[i] = sred[0];
  }
  __syncthreads();
  if (t == 0) {
    float dd = den, best = -1e30f;
    int bj = 0x7fffffff;
    for (int i = 0; i < n; ++i) {
      float e = sexact[i];
      int j = scand_j[i];
      dd += expf(10.f * tanhf(e) - Lref) - expf(10.f * tanhf(scand_a[i]) - Lref);
      if (e > best || (e == best && j < bj)) { best = e; bj = j; }
    }
    out[b] = (float)bj;
    out[32 + b] = expf(10.f * tanhf(best) - Lref) / dd;
  }
}

extern "C" void kernel_launch(void* const* d_in, const int* in_sizes, int n_in,
                              void* d_out, int out_size, void* d_ws, size_t ws_size,
                              hipStream_t stream) {
  const float* x    = (const float*)d_in[0];
  const float* ctx  = (const float*)d_in[1];
  const unsigned char* mask = (const unsigned char*)d_in[2];
  const float* Wi   = (const float*)d_in[3];
  const float* bi   = (const float*)d_in[4];
  const float* Wc0  = (const float*)d_in[5];
  const float* bc0  = (const float*)d_in[6];
  const float* Wc1  = (const float*)d_in[7];
  const float* bc1  = (const float*)d_in[8];
  const float* Wc2  = (const float*)d_in[9];
  const float* bc2  = (const float*)d_in[10];
  const float* Wc3  = (const float*)d_in[11];
  const float* bc3  = (const float*)d_in[12];
  const float* V    = (const float*)d_in[13];
  float* out = (float*)d_out;

  float* inp = (float*)d_ws;             // 16384 f32
  float* att = inp + 16384;              // 262144 f32
  short* Whi = (short*)(att + 262144);   // 1048576 shorts (2 MB)

  hipMemsetAsync(att, 0, 262144 * sizeof(float), stream);
  prep_small_k<<<576, 256, 0, stream>>>(x, Wi, bi, Wc0, Wc1, Wc2, Wc3, Whi, inp);
  gemm_fused_k<<<dim3(8, 256), 512, 0, stream>>>(ctx, Whi,
      inp, bc0, bc1, bc2, bc3, V, att);
  tail_k<<<32, 1024, 0, stream>>>(att, mask, ctx, Wc0, Wc1, Wc2, Wc3,
      bc0, bc1, bc2, bc3, inp, V, out);
}

// Round 16
// 309.061 us; speedup vs baseline: 1.0984x; 1.0984x over previous
//
#include <hip/hip_runtime.h>
#include <math.h>

typedef __bf16 bf16x8 __attribute__((ext_vector_type(8)));
typedef float f32x4 __attribute__((ext_vector_type(4)));
typedef short short8v __attribute__((ext_vector_type(8)));

#define MARGIN 0.01f
#define NCAND 32

#define WAITL  do { asm volatile("s_waitcnt lgkmcnt(0)" ::: "memory"); __builtin_amdgcn_sched_barrier(0); } while (0)
#define WAITV0 do { asm volatile("s_waitcnt vmcnt(0)" ::: "memory"); __builtin_amdgcn_sched_barrier(0); } while (0)
#define BARR   do { __builtin_amdgcn_s_barrier(); __builtin_amdgcn_sched_barrier(0); } while (0)

__device__ __forceinline__ unsigned short f2bf(float f) {
  unsigned u = __float_as_uint(f);
  u += 0x7fffu + ((u >> 16) & 1u);
  return (unsigned short)(u >> 16);
}
__device__ __forceinline__ float tanh_fast(float x) {
  float e = __builtin_amdgcn_exp2f(x * 2.885390081777927f);
  return 1.f - 2.f * __builtin_amdgcn_rcpf(e + 1.f);
}
__device__ __forceinline__ void gl_lds16(const void* g, void* l) {
  __builtin_amdgcn_global_load_lds(
      (const __attribute__((address_space(1))) unsigned int*)g,
      (__attribute__((address_space(3))) unsigned int*)l, 16, 0, 0);
}
// DPP row_shr 16-lane reduce; row sum lands in lane 15 (verified R11).
__device__ __forceinline__ float dpp_row_reduce(float v) {
  int x;
  x = __builtin_amdgcn_update_dpp(0, __builtin_bit_cast(int, v), 0x118, 0xf, 0xf, true);
  v += __builtin_bit_cast(float, x);
  x = __builtin_amdgcn_update_dpp(0, __builtin_bit_cast(int, v), 0x114, 0xf, 0xf, true);
  v += __builtin_bit_cast(float, x);
  x = __builtin_amdgcn_update_dpp(0, __builtin_bit_cast(int, v), 0x112, 0xf, 0xf, true);
  v += __builtin_bit_cast(float, x);
  x = __builtin_amdgcn_update_dpp(0, __builtin_bit_cast(int, v), 0x111, 0xf, 0xf, true);
  v += __builtin_bit_cast(float, x);
  return v;
}

// Fused small prep: blocks [0,512) pack W (bf16, region layout), [512,576) inp.
__global__ __launch_bounds__(256) void prep_small_k(
    const float* __restrict__ x, const float* __restrict__ Wi,
    const float* __restrict__ bi,
    const float* __restrict__ w0, const float* __restrict__ w1,
    const float* __restrict__ w2, const float* __restrict__ w3,
    short* __restrict__ Whi, float* __restrict__ inp) {
  int bid = blockIdx.x;
  if (bid < 512) {
    int gid = bid * 256 + threadIdx.x;   // 131072 chunks of 8
    int c = gid & 3, row = (gid >> 2) & 255, TK = gid >> 10;  // TK = TN*16+KS
    int TN = TK >> 4, KS = TK & 15;
    int n = TN * 256 + row;
    int g = n >> 9, h = n & 511;
    const float* w = (g == 0) ? w0 : (g == 1) ? w1 : (g == 2) ? w2 : w3;
    const float* src = w + (size_t)h * 512 + KS * 32 + c * 8;
    float f[8];
    *(float4*)&f[0] = *(const float4*)(src);
    *(float4*)&f[4] = *(const float4*)(src + 4);
    short8v hv;
    #pragma unroll
    for (int i = 0; i < 8; ++i) hv[i] = (short)f2bf(f[i]);
    *(short8v*)(Whi + (size_t)gid * 8) = hv;
  } else {
    int gid = (bid - 512) * 256 + threadIdx.x;   // 16384
    int b = gid >> 9, h = gid & 511;
    const float* xr = x + b * 512;
    const float* wr = Wi + h * 512;
    float acc = bi[h];
    #pragma unroll 4
    for (int k = 0; k < 512; k += 4) {
      float4 xv = *(const float4*)(xr + k);
      float4 wv = *(const float4*)(wr + k);
      acc += xv.x * wv.x + xv.y * wv.y + xv.z * wv.z + xv.w * wv.w;
    }
    inp[gid] = acc;
  }
}

// Fused GEMM, T14 schedule: 256x256 tile, 16 K-tiles BK=32, 8 waves (2x4).
// Per tile: frag ds_reads | ISSUE next-tile loads (B gl_lds + A fp32->regs)
// | MFMA (hides load latency) | cvt + ds_write (write-late) | barrier.
__global__ __launch_bounds__(512, 2) void gemm_fused_k(
    const float* __restrict__ ctx, const short* __restrict__ Whi,
    const float* __restrict__ inp,
    const float* __restrict__ bc0, const float* __restrict__ bc1,
    const float* __restrict__ bc2, const float* __restrict__ bc3,
    const float* __restrict__ V, float* __restrict__ att) {
  __shared__ __align__(16) short smem[2][2][8192];   // 64 KiB: [slot][A|B]
  __shared__ float sV[256], sPre[256];

  const int t = threadIdx.x;
  int d = blockIdx.x + (blockIdx.y << 3);
  int work = (d & 7) * 256 + (d >> 3);           // XCD-contiguous chunks
  int mt = work >> 3, nt = work & 7;
  int b = mt >> 3;
  int g = nt >> 1, h0 = (nt & 1) * 256;

  if (t < 256) {
    const float* bc = (g == 0) ? bc0 : (g == 1) ? bc1 : (g == 2) ? bc2 : bc3;
    sV[t] = V[h0 + t];
    sPre[t] = inp[b * 512 + h0 + t] + bc[h0 + t];
  }

  const int toff = t * 8;
  // per-thread A staging coords (2 passes over the 256x32 tile)
  const int cc0 = t,        c0 = cc0 & 3, r0 = cc0 >> 2;
  const int cc1 = 512 + t,  c1 = cc1 & 3, r1 = cc1 >> 2;
  const float* aRow0 = ctx + ((size_t)mt * 256 + r0) * 512 + c0 * 8;
  const float* aRow1 = ctx + ((size_t)mt * 256 + r1) * 512 + c1 * 8;

  auto stageB = [&](int tile) {
    const short* gB = Whi + (((size_t)nt * 16 + tile) << 13) + toff;
    short* lB = &smem[tile & 1][1][0];
    gl_lds16(gB,        lB + toff);
    gl_lds16(gB + 4096, lB + toff + 4096);
  };

  f32x4 acc[8][4];
  #pragma unroll
  for (int i = 0; i < 8; ++i)
    #pragma unroll
    for (int j = 0; j < 4; ++j) acc[i][j] = (f32x4){0.f, 0.f, 0.f, 0.f};

  const int lane = t & 63, wid = t >> 6;
  const int wr = wid >> 2, wc = wid & 3;
  const int fr = lane & 15, fq = lane >> 4;
  const int abase = (wr * 128 + fr) * 32 + fq * 8;
  const int bbase = (wc * 64 + fr) * 32 + fq * 8;

  // prologue: tile 0 staged synchronously
  {
    float f0[8], f1[8];
    *(float4*)&f0[0] = *(const float4*)(aRow0);
    *(float4*)&f0[4] = *(const float4*)(aRow0 + 4);
    *(float4*)&f1[0] = *(const float4*)(aRow1);
    *(float4*)&f1[4] = *(const float4*)(aRow1 + 4);
    stageB(0);
    short8v h0v, h1v;
    #pragma unroll
    for (int i = 0; i < 8; ++i) { h0v[i] = (short)f2bf(f0[i]); h1v[i] = (short)f2bf(f1[i]); }
    *(short8v*)(&smem[0][0][r0 * 32 + c0 * 8]) = h0v;
    *(short8v*)(&smem[0][0][r1 * 32 + c1 * 8]) = h1v;
    WAITV0; WAITL;
  }
  BARR;

  float nf0[8], nf1[8];                    // next-tile A fp32 (issue-early regs)
  #pragma unroll 2
  for (int tt = 0; tt < 16; ++tt) {
    const short* sa = &smem[tt & 1][0][0];
    const short* sb = &smem[tt & 1][1][0];
    bf16x8 a[8], b0, b1, b2, b3;
    #pragma unroll
    for (int mi = 0; mi < 8; ++mi)
      a[mi] = *(const bf16x8*)(sa + abase + mi * 512);
    b0 = *(const bf16x8*)(sb + bbase);
    b1 = *(const bf16x8*)(sb + bbase + 512);
    b2 = *(const bf16x8*)(sb + bbase + 1024);
    b3 = *(const bf16x8*)(sb + bbase + 1536);
    if (tt < 15) {
      // T14 issue-early: next tile's loads go out BEFORE the MFMA phase
      int k = (tt + 1) * 32;
      stageB(tt + 1);
      *(float4*)&nf0[0] = *(const float4*)(aRow0 + k);
      *(float4*)&nf0[4] = *(const float4*)(aRow0 + k + 4);
      *(float4*)&nf1[0] = *(const float4*)(aRow1 + k);
      *(float4*)&nf1[4] = *(const float4*)(aRow1 + k + 4);
    }
    WAITL;
    __builtin_amdgcn_s_setprio(1);
    #pragma unroll
    for (int mi = 0; mi < 8; ++mi) {
      acc[mi][0] = __builtin_amdgcn_mfma_f32_16x16x32_bf16(a[mi], b0, acc[mi][0], 0, 0, 0);
      acc[mi][1] = __builtin_amdgcn_mfma_f32_16x16x32_bf16(a[mi], b1, acc[mi][1], 0, 0, 0);
    }
    #pragma unroll
    for (int mi = 0; mi < 8; ++mi) {
      acc[mi][2] = __builtin_amdgcn_mfma_f32_16x16x32_bf16(a[mi], b2, acc[mi][2], 0, 0, 0);
      acc[mi][3] = __builtin_amdgcn_mfma_f32_16x16x32_bf16(a[mi], b3, acc[mi][3], 0, 0, 0);
    }
    __builtin_amdgcn_s_setprio(0);
    __builtin_amdgcn_sched_barrier(0);
    if (tt < 15) {
      WAITV0;                              // loads landed during MFMA
      short8v h0v, h1v;                    // write-late: cvt + 2x ds_write_b128
      #pragma unroll
      for (int i = 0; i < 8; ++i) { h0v[i] = (short)f2bf(nf0[i]); h1v[i] = (short)f2bf(nf1[i]); }
      short* sA1 = &smem[(tt + 1) & 1][0][0];
      *(short8v*)(sA1 + r0 * 32 + c0 * 8) = h0v;
      *(short8v*)(sA1 + r1 * 32 + c1 * 8) = h1v;
      WAITL;                               // drain ds_writes before barrier
    }
    BARR;
  }

  // epilogue: att[b, g*2048 + s] += sum_n V[h]*tanh(pre[h] + Y[n,s])
  float vV[4], vP[4];
  #pragma unroll
  for (int ni = 0; ni < 4; ++ni) {
    int j = wc * 64 + ni * 16 + fr;
    vV[ni] = sV[j];
    vP[ni] = sPre[j];
  }
  size_t abatt = (size_t)b * 8192 + (size_t)g * 2048;
  #pragma unroll
  for (int mi = 0; mi < 8; ++mi) {
    #pragma unroll
    for (int r = 0; r < 4; ++r) {
      float sum = 0.f;
      #pragma unroll
      for (int ni = 0; ni < 4; ++ni)
        sum += vV[ni] * tanh_fast(vP[ni] + acc[mi][ni][r]);
      sum = dpp_row_reduce(sum);
      if (fr == 15) {
        int s = (mt * 256 + wr * 128 + mi * 16 + fq * 4 + r) & 2047;
        atomicAdd(&att[abatt + s], sum);
      }
    }
  }
}

// Tail: max + denom + candidates, exact fp32 rescore, final outputs.
__global__ __launch_bounds__(1024) void tail_k(const float* __restrict__ att,
    const unsigned char* __restrict__ mask, const float* __restrict__ ctx,
    const float* __restrict__ Wc0, const float* __restrict__ Wc1,
    const float* __restrict__ Wc2, const float* __restrict__ Wc3,
    const float* __restrict__ bc0, const float* __restrict__ bc1,
    const float* __restrict__ bc2, const float* __restrict__ bc3,
    const float* __restrict__ inp, const float* __restrict__ V,
    float* __restrict__ out) {
  int b = blockIdx.x, t = threadIdx.x;
  __shared__ float sred[1024];
  __shared__ float sctx[512];
  __shared__ int scnt;
  __shared__ int scand_j[NCAND];
  __shared__ float scand_a[NCAND];
  __shared__ float sexact[NCAND];

  if (t == 0) scnt = 0;
  float bm = -1e30f;
  for (int j = t; j < 8192; j += 1024) {
    if (mask[b * 2048 + (j & 2047)]) continue;
    bm = fmaxf(bm, att[(size_t)b * 8192 + j]);
  }
  sred[t] = bm;
  __syncthreads();
  for (int s2 = 512; s2 > 0; s2 >>= 1) {
    if (t < s2) sred[t] = fmaxf(sred[t], sred[t + s2]);
    __syncthreads();
  }
  float mx = sred[0];
  float Lref = 10.f * tanhf(mx);
  __syncthreads();
  float se = 0.f;
  for (int j = t; j < 8192; j += 1024) {
    if (mask[b * 2048 + (j & 2047)]) continue;
    float a = att[(size_t)b * 8192 + j];
    se += expf(10.f * tanhf(a) - Lref);
    if (a >= mx - MARGIN) {
      int slot = atomicAdd(&scnt, 1);
      if (slot < NCAND) { scand_j[slot] = j; scand_a[slot] = a; }
    }
  }
  sred[t] = se;
  __syncthreads();
  for (int s2 = 512; s2 > 0; s2 >>= 1) {
    if (t < s2) sred[t] += sred[t + s2];
    __syncthreads();
  }
  float den = sred[0];
  int n = min(scnt, NCAND);
  for (int j = t; j < 2048; j += 1024)
    out[64 + b * 2048 + j] = mask[b * 2048 + j] ? 1.0f : 0.0f;
  for (int i = 0; i < n; ++i) {
    int jj = scand_j[i];
    int g = jj >> 11, s = jj & 2047;
    const float* W  = (g == 0) ? Wc0 : (g == 1) ? Wc1 : (g == 2) ? Wc2 : Wc3;
    const float* bc = (g == 0) ? bc0 : (g == 1) ? bc1 : (g == 2) ? bc2 : bc3;
    const float* cr = ctx + ((size_t)b * 2048 + s) * 512;
    __syncthreads();
    if (t < 512) sctx[t] = cr[t];
    __syncthreads();
    float total = 0.f;
    if (t < 512) {
      const float* wrp = W + (size_t)t * 512;
      float acc = 0.f;
      #pragma unroll 4
      for (int k = 0; k < 512; k += 4) {
        float4 wv = *(const float4*)(wrp + k);
        acc += wv.x * sctx[k] + wv.y * sctx[k + 1] + wv.z * sctx[k + 2] + wv.w * sctx[k + 3];
      }
      total = V[t] * tanhf(inp[b * 512 + t] + bc[t] + acc);
    }
    sred[t] = total;
    __syncthreads();
    for (int s2 = 512; s2 > 0; s2 >>= 1) {
      if (t < s2) sred[t] += sred[t + s2];
      __syncthreads();
    }
    if (t == 0) sexact[i] = sred[0];
  }
  __syncthreads();
  if (t == 0) {
    float dd = den, best = -1e30f;
    int bj = 0x7fffffff;
    for (int i = 0; i < n; ++i) {
      float e = sexact[i];
      int j = scand_j[i];
      dd += expf(10.f * tanhf(e) - Lref) - expf(10.f * tanhf(scand_a[i]) - Lref);
      if (e > best || (e == best && j < bj)) { best = e; bj = j; }
    }
    out[b] = (float)bj;
    out[32 + b] = expf(10.f * tanhf(best) - Lref) / dd;
  }
}

extern "C" void kernel_launch(void* const* d_in, const int* in_sizes, int n_in,
                              void* d_out, int out_size, void* d_ws, size_t ws_size,
                              hipStream_t stream) {
  const float* x    = (const float*)d_in[0];
  const float* ctx  = (const float*)d_in[1];
  const unsigned char* mask = (const unsigned char*)d_in[2];
  const float* Wi   = (const float*)d_in[3];
  const float* bi   = (const float*)d_in[4];
  const float* Wc0  = (const float*)d_in[5];
  const float* bc0  = (const float*)d_in[6];
  const float* Wc1  = (const float*)d_in[7];
  const float* bc1  = (const float*)d_in[8];
  const float* Wc2  = (const float*)d_in[9];
  const float* bc2  = (const float*)d_in[10];
  const float* Wc3  = (const float*)d_in[11];
  const float* bc3  = (const float*)d_in[12];
  const float* V    = (const float*)d_in[13];
  float* out = (float*)d_out;

  float* inp = (float*)d_ws;             // 16384 f32
  float* att = inp + 16384;              // 262144 f32
  short* Whi = (short*)(att + 262144);   // 1048576 shorts (2 MB)

  hipMemsetAsync(att, 0, 262144 * sizeof(float), stream);
  prep_small_k<<<576, 256, 0, stream>>>(x, Wi, bi, Wc0, Wc1, Wc2, Wc3, Whi, inp);
  gemm_fused_k<<<dim3(8, 256), 512, 0, stream>>>(ctx, Whi,
      inp, bc0, bc1, bc2, bc3, V, att);
  tail_k<<<32, 1024, 0, stream>>>(att, mask, ctx, Wc0, Wc1, Wc2, Wc3,
      bc0, bc1, bc2, bc3, inp, V, out);
}

// Round 17
// 303.010 us; speedup vs baseline: 1.1203x; 1.0200x over previous
//
#include <hip/hip_runtime.h>
#include <math.h>

typedef __bf16 bf16x8 __attribute__((ext_vector_type(8)));
typedef float f32x4 __attribute__((ext_vector_type(4)));
typedef short short8v __attribute__((ext_vector_type(8)));

#define MARGIN 0.01f
#define NCAND 32

#define WAITL  do { asm volatile("s_waitcnt lgkmcnt(0)" ::: "memory"); __builtin_amdgcn_sched_barrier(0); } while (0)
#define WAITV0 do { asm volatile("s_waitcnt vmcnt(0)" ::: "memory"); __builtin_amdgcn_sched_barrier(0); } while (0)
#define BARR   do { __builtin_amdgcn_s_barrier(); __builtin_amdgcn_sched_barrier(0); } while (0)

__device__ __forceinline__ unsigned short f2bf(float f) {
  unsigned u = __float_as_uint(f);
  u += 0x7fffu + ((u >> 16) & 1u);
  return (unsigned short)(u >> 16);
}
__device__ __forceinline__ float tanh_fast(float x) {
  float e = __builtin_amdgcn_exp2f(x * 2.885390081777927f);
  return 1.f - 2.f * __builtin_amdgcn_rcpf(e + 1.f);
}
__device__ __forceinline__ void gl_lds16(const void* g, void* l) {
  __builtin_amdgcn_global_load_lds(
      (const __attribute__((address_space(1))) unsigned int*)g,
      (__attribute__((address_space(3))) unsigned int*)l, 16, 0, 0);
}
// DPP row_shr 16-lane reduce; row sum lands in lane 15 (verified R11).
__device__ __forceinline__ float dpp_row_reduce(float v) {
  int x;
  x = __builtin_amdgcn_update_dpp(0, __builtin_bit_cast(int, v), 0x118, 0xf, 0xf, true);
  v += __builtin_bit_cast(float, x);
  x = __builtin_amdgcn_update_dpp(0, __builtin_bit_cast(int, v), 0x114, 0xf, 0xf, true);
  v += __builtin_bit_cast(float, x);
  x = __builtin_amdgcn_update_dpp(0, __builtin_bit_cast(int, v), 0x112, 0xf, 0xf, true);
  v += __builtin_bit_cast(float, x);
  x = __builtin_amdgcn_update_dpp(0, __builtin_bit_cast(int, v), 0x111, 0xf, 0xf, true);
  v += __builtin_bit_cast(float, x);
  return v;
}

// Fused prep for BN=512 layout. ctx_blocks = 16384 when packing ctx, else 0.
// blocks [0,ctx_blocks): ctx pack -> Chi regions (MT 0..511, KS 0..15) 128r x 32k
// next 512: W pack -> Whi regions (TN 0..3, KS 0..15) 512n x 32k
// last 64: inp
__global__ __launch_bounds__(256) void prep_all_k(
    const float* __restrict__ ctx, const float* __restrict__ x,
    const float* __restrict__ Wi, const float* __restrict__ bi,
    const float* __restrict__ w0, const float* __restrict__ w1,
    const float* __restrict__ w2, const float* __restrict__ w3,
    short* __restrict__ Chi, short* __restrict__ Whi, float* __restrict__ inp,
    int ctx_blocks) {
  int bid = blockIdx.x;
  if (bid < ctx_blocks) {
    int gid = bid * 256 + threadIdx.x;   // 4194304 chunks of 8
    int c = gid & 3, row = (gid >> 2) & 127, TK = gid >> 9;  // TK = MT*16+KS
    int MT = TK >> 4, KS = TK & 15;
    size_t m = (size_t)MT * 128 + row;
    int k = KS * 32 + c * 8;
    float f[8];
    *(float4*)&f[0] = *(const float4*)(ctx + m * 512 + k);
    *(float4*)&f[4] = *(const float4*)(ctx + m * 512 + k + 4);
    short8v hv;
    #pragma unroll
    for (int i = 0; i < 8; ++i) hv[i] = (short)f2bf(f[i]);
    *(short8v*)(Chi + (size_t)gid * 8) = hv;
  } else if (bid < ctx_blocks + 512) {
    int gid = (bid - ctx_blocks) * 256 + threadIdx.x;   // 131072 chunks
    int c = gid & 3, row = (gid >> 2) & 511, TK = gid >> 11;  // TK = TN*16+KS
    int TN = TK >> 4, KS = TK & 15;
    const float* w = (TN == 0) ? w0 : (TN == 1) ? w1 : (TN == 2) ? w2 : w3;
    const float* src = w + (size_t)row * 512 + KS * 32 + c * 8;
    float f[8];
    *(float4*)&f[0] = *(const float4*)(src);
    *(float4*)&f[4] = *(const float4*)(src + 4);
    short8v hv;
    #pragma unroll
    for (int i = 0; i < 8; ++i) hv[i] = (short)f2bf(f[i]);
    *(short8v*)(Whi + (size_t)gid * 8) = hv;
  } else {
    int gid = (bid - ctx_blocks - 512) * 256 + threadIdx.x;   // 16384
    int b = gid >> 9, h = gid & 511;
    const float* xr = x + b * 512;
    const float* wr = Wi + h * 512;
    float acc = bi[h];
    #pragma unroll 4
    for (int k = 0; k < 512; k += 4) {
      float4 xv = *(const float4*)(xr + k);
      float4 wv = *(const float4*)(wr + k);
      acc += xv.x * wv.x + xv.y * wv.y + xv.z * wv.z + xv.w * wv.w;
    }
    inp[gid] = acc;
  }
}

// GEMM, BN=512 geometry: 128x512 tile, 16 K-tiles BK=32, 16 waves (2wr x 8wc),
// per-wave 64x64 (acc 64 VGPR). A-redundancy 4x (was 8x). One weight group
// per block (g = nt). 2-slot LDS ring (80 KB), drain per tile.
template<bool PRESPLIT>
__global__ __launch_bounds__(1024, 4) void gemm_att_k(
    const float* __restrict__ ctx, const short* __restrict__ Chi,
    const short* __restrict__ Whi,
    const float* __restrict__ inp,
    const float* __restrict__ bc0, const float* __restrict__ bc1,
    const float* __restrict__ bc2, const float* __restrict__ bc3,
    const float* __restrict__ V, float* __restrict__ att) {
  __shared__ __align__(16) short smem[2][20480];   // 80 KiB: [slot][A4096|B16384]

  const int t = threadIdx.x;
  int d = blockIdx.x + (blockIdx.y << 3);
  int work = (d & 7) * 256 + (d >> 3);           // XCD-contiguous chunks
  int mt = work >> 2, nt = work & 3;             // mt: 128-row strip, nt: 512-col
  int b = mt >> 4;
  const float* bc = (nt == 0) ? bc0 : (nt == 1) ? bc1 : (nt == 2) ? bc2 : bc3;

  auto stageA = [&](int tile, int slot) {
    if (t < 512)
      gl_lds16(Chi + (((size_t)mt * 16 + tile) << 12) + t * 8, &smem[slot][t * 8]);
  };
  auto stageB = [&](int tile, int slot) {
    const short* gB = Whi + (((size_t)nt * 16 + tile) << 14) + t * 8;
    short* lB = &smem[slot][4096 + t * 8];
    gl_lds16(gB,        lB);
    gl_lds16(gB + 8192, lB + 8192);
  };
  auto stageA_reg = [&](int tile, int slot) {   // fallback: fp32 -> bf16 ds_write
    if (t < 512) {
      int c = t & 3, r = t >> 2;
      const float* src = ctx + ((size_t)mt * 128 + r) * 512 + tile * 32 + c * 8;
      float f[8];
      *(float4*)&f[0] = *(const float4*)src;
      *(float4*)&f[4] = *(const float4*)(src + 4);
      short8v hv;
      #pragma unroll
      for (int i = 0; i < 8; ++i) hv[i] = (short)f2bf(f[i]);
      *(short8v*)(&smem[slot][r * 32 + c * 8]) = hv;
    }
  };

  f32x4 acc[4][4];
  #pragma unroll
  for (int i = 0; i < 4; ++i)
    #pragma unroll
    for (int j = 0; j < 4; ++j) acc[i][j] = (f32x4){0.f, 0.f, 0.f, 0.f};

  const int lane = t & 63, wid = t >> 6;         // 16 waves
  const int wr = wid >> 3, wc = wid & 7;         // 2 x 8
  const int fr = lane & 15, fq = lane >> 4;
  const int abase = (wr * 64 + fr) * 32 + fq * 8;          // A: 128 rows
  const int bbase = 4096 + (wc * 64 + fr) * 32 + fq * 8;   // B: 512 rows

  if constexpr (PRESPLIT) { stageA(0, 0); stageB(0, 0); WAITV0; }
  else { stageA_reg(0, 0); stageB(0, 0); WAITV0; WAITL; }
  BARR;

  #pragma unroll 2
  for (int tt = 0; tt < 16; ++tt) {
    const int slot = tt & 1;
    const short* s = &smem[slot][0];
    bf16x8 a[4], bv[4];
    #pragma unroll
    for (int mi = 0; mi < 4; ++mi) a[mi] = *(const bf16x8*)(s + abase + mi * 512);
    #pragma unroll
    for (int ni = 0; ni < 4; ++ni) bv[ni] = *(const bf16x8*)(s + bbase + ni * 512);
    if (tt < 15) {
      if constexpr (PRESPLIT) { stageA(tt + 1, slot ^ 1); }
      stageB(tt + 1, slot ^ 1);
    }
    WAITL;
    __builtin_amdgcn_s_setprio(1);
    #pragma unroll
    for (int mi = 0; mi < 4; ++mi)
      #pragma unroll
      for (int ni = 0; ni < 4; ++ni)
        acc[mi][ni] = __builtin_amdgcn_mfma_f32_16x16x32_bf16(a[mi], bv[ni], acc[mi][ni], 0, 0, 0);
    __builtin_amdgcn_s_setprio(0);
    __builtin_amdgcn_sched_barrier(0);
    if (tt < 15) {
      if constexpr (!PRESPLIT) { stageA_reg(tt + 1, slot ^ 1); WAITL; }
      WAITV0;
    }
    BARR;
  }

  // epilogue: att[b, nt*2048 + s] += this wave's 64-col partial
  float vV[4], vP[4];
  #pragma unroll
  for (int ni = 0; ni < 4; ++ni) {
    int j = wc * 64 + ni * 16 + fr;
    vV[ni] = V[j];
    vP[ni] = inp[b * 512 + j] + bc[j];
  }
  size_t abatt = (size_t)b * 8192 + (size_t)nt * 2048;
  #pragma unroll
  for (int mi = 0; mi < 4; ++mi) {
    #pragma unroll
    for (int r = 0; r < 4; ++r) {
      float sum = 0.f;
      #pragma unroll
      for (int ni = 0; ni < 4; ++ni)
        sum += vV[ni] * tanh_fast(vP[ni] + acc[mi][ni][r]);
      sum = dpp_row_reduce(sum);
      if (fr == 15) {
        int s2 = (mt & 15) * 128 + wr * 64 + mi * 16 + fq * 4 + r;
        atomicAdd(&att[abatt + s2], sum);
      }
    }
  }
}

// Tail: max + denom + candidates, exact fp32 rescore, final outputs.
__global__ __launch_bounds__(1024) void tail_k(const float* __restrict__ att,
    const unsigned char* __restrict__ mask, const float* __restrict__ ctx,
    const float* __restrict__ Wc0, const float* __restrict__ Wc1,
    const float* __restrict__ Wc2, const float* __restrict__ Wc3,
    const float* __restrict__ bc0, const float* __restrict__ bc1,
    const float* __restrict__ bc2, const float* __restrict__ bc3,
    const float* __restrict__ inp, const float* __restrict__ V,
    float* __restrict__ out) {
  int b = blockIdx.x, t = threadIdx.x;
  __shared__ float sred[1024];
  __shared__ float sctx[512];
  __shared__ int scnt;
  __shared__ int scand_j[NCAND];
  __shared__ float scand_a[NCAND];
  __shared__ float sexact[NCAND];

  if (t == 0) scnt = 0;
  float bm = -1e30f;
  for (int j = t; j < 8192; j += 1024) {
    if (mask[b * 2048 + (j & 2047)]) continue;
    bm = fmaxf(bm, att[(size_t)b * 8192 + j]);
  }
  sred[t] = bm;
  __syncthreads();
  for (int s2 = 512; s2 > 0; s2 >>= 1) {
    if (t < s2) sred[t] = fmaxf(sred[t], sred[t + s2]);
    __syncthreads();
  }
  float mx = sred[0];
  float Lref = 10.f * tanhf(mx);
  __syncthreads();
  float se = 0.f;
  for (int j = t; j < 8192; j += 1024) {
    if (mask[b * 2048 + (j & 2047)]) continue;
    float a = att[(size_t)b * 8192 + j];
    se += expf(10.f * tanhf(a) - Lref);
    if (a >= mx - MARGIN) {
      int slot = atomicAdd(&scnt, 1);
      if (slot < NCAND) { scand_j[slot] = j; scand_a[slot] = a; }
    }
  }
  sred[t] = se;
  __syncthreads();
  for (int s2 = 512; s2 > 0; s2 >>= 1) {
    if (t < s2) sred[t] += sred[t + s2];
    __syncthreads();
  }
  float den = sred[0];
  int n = min(scnt, NCAND);
  for (int j = t; j < 2048; j += 1024)
    out[64 + b * 2048 + j] = mask[b * 2048 + j] ? 1.0f : 0.0f;
  for (int i = 0; i < n; ++i) {
    int jj = scand_j[i];
    int g = jj >> 11, s = jj & 2047;
    const float* W  = (g == 0) ? Wc0 : (g == 1) ? Wc1 : (g == 2) ? Wc2 : Wc3;
    const float* bc = (g == 0) ? bc0 : (g == 1) ? bc1 : (g == 2) ? bc2 : bc3;
    const float* cr = ctx + ((size_t)b * 2048 + s) * 512;
    __syncthreads();
    if (t < 512) sctx[t] = cr[t];
    __syncthreads();
    float total = 0.f;
    if (t < 512) {
      const float* wrp = W + (size_t)t * 512;
      float acc = 0.f;
      #pragma unroll 4
      for (int k = 0; k < 512; k += 4) {
        float4 wv = *(const float4*)(wrp + k);
        acc += wv.x * sctx[k] + wv.y * sctx[k + 1] + wv.z * sctx[k + 2] + wv.w * sctx[k + 3];
      }
      total = V[t] * tanhf(inp[b * 512 + t] + bc[t] + acc);
    }
    sred[t] = total;
    __syncthreads();
    for (int s2 = 512; s2 > 0; s2 >>= 1) {
      if (t < s2) sred[t] += sred[t + s2];
      __syncthreads();
    }
    if (t == 0) sexact[i] = sred[0];
  }
  __syncthreads();
  if (t == 0) {
    float dd = den, best = -1e30f;
    int bj = 0x7fffffff;
    for (int i = 0; i < n; ++i) {
      float e = sexact[i];
      int j = scand_j[i];
      dd += expf(10.f * tanhf(e) - Lref) - expf(10.f * tanhf(scand_a[i]) - Lref);
      if (e > best || (e == best && j < bj)) { best = e; bj = j; }
    }
    out[b] = (float)bj;
    out[32 + b] = expf(10.f * tanhf(best) - Lref) / dd;
  }
}

extern "C" void kernel_launch(void* const* d_in, const int* in_sizes, int n_in,
                              void* d_out, int out_size, void* d_ws, size_t ws_size,
                              hipStream_t stream) {
  const float* x    = (const float*)d_in[0];
  const float* ctx  = (const float*)d_in[1];
  const unsigned char* mask = (const unsigned char*)d_in[2];
  const float* Wi   = (const float*)d_in[3];
  const float* bi   = (const float*)d_in[4];
  const float* Wc0  = (const float*)d_in[5];
  const float* bc0  = (const float*)d_in[6];
  const float* Wc1  = (const float*)d_in[7];
  const float* bc1  = (const float*)d_in[8];
  const float* Wc2  = (const float*)d_in[9];
  const float* bc2  = (const float*)d_in[10];
  const float* Wc3  = (const float*)d_in[11];
  const float* bc3  = (const float*)d_in[12];
  const float* V    = (const float*)d_in[13];
  float* out = (float*)d_out;

  float* inp = (float*)d_ws;             // 16384 f32
  float* att = inp + 16384;              // 262144 f32
  short* Whi = (short*)(att + 262144);   // 1048576 shorts
  short* Chi = Whi + 1048576;            // 33554432 shorts
  size_t need = (size_t)((char*)(Chi + 33554432) - (char*)d_ws);
  bool presplit = ws_size >= need;

  hipMemsetAsync(att, 0, 262144 * sizeof(float), stream);
  if (presplit) {
    prep_all_k<<<16960, 256, 0, stream>>>(ctx, x, Wi, bi,
        Wc0, Wc1, Wc2, Wc3, Chi, Whi, inp, 16384);
    gemm_att_k<true><<<dim3(8, 256), 1024, 0, stream>>>(ctx, Chi, Whi,
        inp, bc0, bc1, bc2, bc3, V, att);
  } else {
    prep_all_k<<<576, 256, 0, stream>>>(ctx, x, Wi, bi,
        Wc0, Wc1, Wc2, Wc3, nullptr, Whi, inp, 0);
    gemm_att_k<false><<<dim3(8, 256), 1024, 0, stream>>>(ctx, nullptr, Whi,
        inp, bc0, bc1, bc2, bc3, V, att);
  }
  tail_k<<<32, 1024, 0, stream>>>(att, mask, ctx, Wc0, Wc1, Wc2, Wc3,
      bc0, bc1, bc2, bc3, inp, V, out);
}

// Round 18
// 291.537 us; speedup vs baseline: 1.1644x; 1.0394x over previous
//
#include <hip/hip_runtime.h>
#include <math.h>

typedef __bf16 bf16x8 __attribute__((ext_vector_type(8)));
typedef float f32x4 __attribute__((ext_vector_type(4)));
typedef short short8v __attribute__((ext_vector_type(8)));

#define MARGIN 0.01f
#define NCAND 32

#define WAITL  do { asm volatile("s_waitcnt lgkmcnt(0)" ::: "memory"); __builtin_amdgcn_sched_barrier(0); } while (0)
#define WAITV0 do { asm volatile("s_waitcnt vmcnt(0)" ::: "memory"); __builtin_amdgcn_sched_barrier(0); } while (0)
#define WAITV3 do { asm volatile("s_waitcnt vmcnt(3)" ::: "memory"); __builtin_amdgcn_sched_barrier(0); } while (0)
#define BARR   do { __builtin_amdgcn_s_barrier(); __builtin_amdgcn_sched_barrier(0); } while (0)

__device__ __forceinline__ unsigned short f2bf(float f) {
  unsigned u = __float_as_uint(f);
  u += 0x7fffu + ((u >> 16) & 1u);
  return (unsigned short)(u >> 16);
}
__device__ __forceinline__ float tanh_fast(float x) {
  float e = __builtin_amdgcn_exp2f(x * 2.885390081777927f);
  return 1.f - 2.f * __builtin_amdgcn_rcpf(e + 1.f);
}
__device__ __forceinline__ void gl_lds16(const void* g, void* l) {
  __builtin_amdgcn_global_load_lds(
      (const __attribute__((address_space(1))) unsigned int*)g,
      (__attribute__((address_space(3))) unsigned int*)l, 16, 0, 0);
}
// pack 2 fp32 -> 2 bf16 (RNE), 1 instruction
__device__ __forceinline__ int cvt_pk_bf16(float lo, float hi) {
  int r;
  asm("v_cvt_pk_bf16_f32 %0, %1, %2" : "=v"(r) : "v"(lo), "v"(hi));
  return r;
}
// DPP row_shr 16-lane reduce; row sum lands in lane 15 (verified R11).
__device__ __forceinline__ float dpp_row_reduce(float v) {
  int x;
  x = __builtin_amdgcn_update_dpp(0, __builtin_bit_cast(int, v), 0x118, 0xf, 0xf, true);
  v += __builtin_bit_cast(float, x);
  x = __builtin_amdgcn_update_dpp(0, __builtin_bit_cast(int, v), 0x114, 0xf, 0xf, true);
  v += __builtin_bit_cast(float, x);
  x = __builtin_amdgcn_update_dpp(0, __builtin_bit_cast(int, v), 0x112, 0xf, 0xf, true);
  v += __builtin_bit_cast(float, x);
  x = __builtin_amdgcn_update_dpp(0, __builtin_bit_cast(int, v), 0x111, 0xf, 0xf, true);
  v += __builtin_bit_cast(float, x);
  return v;
}

// Small prep: blocks [0,512) pack W -> Whi regions (TN 0..3, KS 0..15) of
// 512 rows x 32 k bf16 (R17 layout); blocks [512,576) inp.
__global__ __launch_bounds__(256) void prep_small_k(
    const float* __restrict__ x, const float* __restrict__ Wi,
    const float* __restrict__ bi,
    const float* __restrict__ w0, const float* __restrict__ w1,
    const float* __restrict__ w2, const float* __restrict__ w3,
    short* __restrict__ Whi, float* __restrict__ inp) {
  int bid = blockIdx.x;
  if (bid < 512) {
    int gid = bid * 256 + threadIdx.x;   // 131072 chunks of 8
    int c = gid & 3, row = (gid >> 2) & 511, TK = gid >> 11;  // TK = TN*16+KS
    int TN = TK >> 4, KS = TK & 15;
    const float* w = (TN == 0) ? w0 : (TN == 1) ? w1 : (TN == 2) ? w2 : w3;
    const float* src = w + (size_t)row * 512 + KS * 32 + c * 8;
    float f[8];
    *(float4*)&f[0] = *(const float4*)(src);
    *(float4*)&f[4] = *(const float4*)(src + 4);
    short8v hv;
    #pragma unroll
    for (int i = 0; i < 8; ++i) hv[i] = (short)f2bf(f[i]);
    *(short8v*)(Whi + (size_t)gid * 8) = hv;
  } else {
    int gid = (bid - 512) * 256 + threadIdx.x;   // 16384
    int b = gid >> 9, h = gid & 511;
    const float* xr = x + b * 512;
    const float* wr = Wi + h * 512;
    float acc = bi[h];
    #pragma unroll 4
    for (int k = 0; k < 512; k += 4) {
      float4 xv = *(const float4*)(xr + k);
      float4 wv = *(const float4*)(wr + k);
      acc += xv.x * wv.x + xv.y * wv.y + xv.z * wv.z + xv.w * wv.w;
    }
    inp[gid] = acc;
  }
}

// GEMM, BN=512 geometry, A DIRECT from fp32 ctx:
// 128x512 tile, 16 K-tiles BK=32, 16 waves (2wr x 8wc), per-wave 64x64.
// A: per-lane-gather global_load_lds (XOR chunk-swizzled source, rule #21),
//    fp32 in LDS, cvt_pk->bf16 at frag read. B: packed Whi via gl_lds.
// 3-slot ring (48 KB/slot = 144 KB), stage t+2, counted vmcnt(3).
__global__ __launch_bounds__(1024, 4) void gemm_att_k(
    const float* __restrict__ ctx, const short* __restrict__ Whi,
    const float* __restrict__ inp,
    const float* __restrict__ bc0, const float* __restrict__ bc1,
    const float* __restrict__ bc2, const float* __restrict__ bc3,
    const float* __restrict__ V, float* __restrict__ att) {
  __shared__ __align__(16) char smem[3][49152];   // [slot][A fp32 16K | B bf16 32K]

  const int t = threadIdx.x;
  int d = blockIdx.x + (blockIdx.y << 3);
  int work = (d & 7) * 256 + (d >> 3);           // XCD-contiguous chunks
  int mt = work >> 2, nt = work & 3;             // 4 nt-blocks share mt's A (L2)
  int b = mt >> 4;
  const float* bc = (nt == 0) ? bc0 : (nt == 1) ? bc1 : (nt == 2) ? bc2 : bc3;

  // A gather coords: lane t covers row r=t>>3, stored 16B-chunk position t&7,
  // which holds DATA chunk (t&7)^(r&7)  -> conflict-free swizzled reads.
  const int ar = t >> 3, apos = t & 7;
  const int aq = apos ^ (ar & 7);
  const float* aSrc = ctx + ((size_t)mt * 128 + ar) * 512 + aq * 4;

  auto stageA = [&](int tile, int slot) {
    gl_lds16(aSrc + tile * 32, (float*)&smem[slot][0] + t * 4);
  };
  auto stageB = [&](int tile, int slot) {
    const short* gB = Whi + (((size_t)nt * 16 + tile) << 14) + t * 8;
    short* lB = (short*)&smem[slot][16384] + t * 8;
    gl_lds16(gB,        lB);
    gl_lds16(gB + 8192, lB + 8192);
  };

  f32x4 acc[4][4];
  #pragma unroll
  for (int i = 0; i < 4; ++i)
    #pragma unroll
    for (int j = 0; j < 4; ++j) acc[i][j] = (f32x4){0.f, 0.f, 0.f, 0.f};

  const int lane = t & 63, wid = t >> 6;         // 16 waves
  const int wr = wid >> 3, wc = wid & 7;         // 2 x 8
  const int fr = lane & 15, fq = lane >> 4;
  // A frag: row = wr*64+mi*16+fr; row&7 == fr&7. Data chunks q0=fq*2, q1=q0+1
  // live at positions p0=q0^(fr&7), p1=p0^1.
  const int s7 = fr & 7;
  const int p0 = (fq * 2) ^ s7;                  // f32 offset = row*32 + p*4
  const int bbase = (wc * 64 + fr) * 32 + fq * 8;   // shorts, 512-row B

  stageA(0, 0); stageB(0, 0);
  stageA(1, 1); stageB(1, 1);
  WAITV3;                                        // tile 0 in, tile 1 flying
  BARR;

  #pragma unroll
  for (int tt = 0; tt < 16; ++tt) {
    const int slot = tt % 3;
    const float* As = (const float*)&smem[slot][0];
    const short* Bs = (const short*)&smem[slot][16384];
    if (tt < 14) { stageA(tt + 2, (tt + 2) % 3); stageB(tt + 2, (tt + 2) % 3); }
    bf16x8 a[4], bv[4];
    #pragma unroll
    for (int mi = 0; mi < 4; ++mi) {
      int rowb = (wr * 64 + mi * 16 + fr) * 32;
      f32x4 c0 = *(const f32x4*)(As + rowb + p0 * 4);
      f32x4 c1 = *(const f32x4*)(As + rowb + (p0 ^ 1) * 4);
      int4 w;
      w.x = cvt_pk_bf16(c0[0], c0[1]);
      w.y = cvt_pk_bf16(c0[2], c0[3]);
      w.z = cvt_pk_bf16(c1[0], c1[1]);
      w.w = cvt_pk_bf16(c1[2], c1[3]);
      a[mi] = __builtin_bit_cast(bf16x8, w);
    }
    #pragma unroll
    for (int ni = 0; ni < 4; ++ni) bv[ni] = *(const bf16x8*)(Bs + bbase + ni * 512);
    WAITL;
    __builtin_amdgcn_s_setprio(1);
    #pragma unroll
    for (int mi = 0; mi < 4; ++mi)
      #pragma unroll
      for (int ni = 0; ni < 4; ++ni)
        acc[mi][ni] = __builtin_amdgcn_mfma_f32_16x16x32_bf16(a[mi], bv[ni], acc[mi][ni], 0, 0, 0);
    __builtin_amdgcn_s_setprio(0);
    __builtin_amdgcn_sched_barrier(0);
    if (tt < 14) { WAITV3; }                     // tile tt+1 done, tt+2 flying
    else if (tt == 14) { WAITV0; }               // drain last stage
    BARR;
  }

  // epilogue: att[b, nt*2048 + s] += this wave's 64-col partial
  float vV[4], vP[4];
  #pragma unroll
  for (int ni = 0; ni < 4; ++ni) {
    int j = wc * 64 + ni * 16 + fr;
    vV[ni] = V[j];
    vP[ni] = inp[b * 512 + j] + bc[j];
  }
  size_t abatt = (size_t)b * 8192 + (size_t)nt * 2048;
  #pragma unroll
  for (int mi = 0; mi < 4; ++mi) {
    #pragma unroll
    for (int r = 0; r < 4; ++r) {
      float sum = 0.f;
      #pragma unroll
      for (int ni = 0; ni < 4; ++ni)
        sum += vV[ni] * tanh_fast(vP[ni] + acc[mi][ni][r]);
      sum = dpp_row_reduce(sum);
      if (fr == 15) {
        int s2 = (mt & 15) * 128 + wr * 64 + mi * 16 + fq * 4 + r;
        atomicAdd(&att[abatt + s2], sum);
      }
    }
  }
}

// Tail: max + denom + candidates, exact fp32 rescore, final outputs.
__global__ __launch_bounds__(1024) void tail_k(const float* __restrict__ att,
    const unsigned char* __restrict__ mask, const float* __restrict__ ctx,
    const float* __restrict__ Wc0, const float* __restrict__ Wc1,
    const float* __restrict__ Wc2, const float* __restrict__ Wc3,
    const float* __restrict__ bc0, const float* __restrict__ bc1,
    const float* __restrict__ bc2, const float* __restrict__ bc3,
    const float* __restrict__ inp, const float* __restrict__ V,
    float* __restrict__ out) {
  int b = blockIdx.x, t = threadIdx.x;
  __shared__ float sred[1024];
  __shared__ float sctx[512];
  __shared__ int scnt;
  __shared__ int scand_j[NCAND];
  __shared__ float scand_a[NCAND];
  __shared__ float sexact[NCAND];

  if (t == 0) scnt = 0;
  float bm = -1e30f;
  for (int j = t; j < 8192; j += 1024) {
    if (mask[b * 2048 + (j & 2047)]) continue;
    bm = fmaxf(bm, att[(size_t)b * 8192 + j]);
  }
  sred[t] = bm;
  __syncthreads();
  for (int s2 = 512; s2 > 0; s2 >>= 1) {
    if (t < s2) sred[t] = fmaxf(sred[t], sred[t + s2]);
    __syncthreads();
  }
  float mx = sred[0];
  float Lref = 10.f * tanhf(mx);
  __syncthreads();
  float se = 0.f;
  for (int j = t; j < 8192; j += 1024) {
    if (mask[b * 2048 + (j & 2047)]) continue;
    float a = att[(size_t)b * 8192 + j];
    se += expf(10.f * tanhf(a) - Lref);
    if (a >= mx - MARGIN) {
      int slot = atomicAdd(&scnt, 1);
      if (slot < NCAND) { scand_j[slot] = j; scand_a[slot] = a; }
    }
  }
  sred[t] = se;
  __syncthreads();
  for (int s2 = 512; s2 > 0; s2 >>= 1) {
    if (t < s2) sred[t] += sred[t + s2];
    __syncthreads();
  }
  float den = sred[0];
  int n = min(scnt, NCAND);
  for (int j = t; j < 2048; j += 1024)
    out[64 + b * 2048 + j] = mask[b * 2048 + j] ? 1.0f : 0.0f;
  for (int i = 0; i < n; ++i) {
    int jj = scand_j[i];
    int g = jj >> 11, s = jj & 2047;
    const float* W  = (g == 0) ? Wc0 : (g == 1) ? Wc1 : (g == 2) ? Wc2 : Wc3;
    const float* bc = (g == 0) ? bc0 : (g == 1) ? bc1 : (g == 2) ? bc2 : bc3;
    const float* cr = ctx + ((size_t)b * 2048 + s) * 512;
    __syncthreads();
    if (t < 512) sctx[t] = cr[t];
    __syncthreads();
    float total = 0.f;
    if (t < 512) {
      const float* wrp = W + (size_t)t * 512;
      float acc = 0.f;
      #pragma unroll 4
      for (int k = 0; k < 512; k += 4) {
        float4 wv = *(const float4*)(wrp + k);
        acc += wv.x * sctx[k] + wv.y * sctx[k + 1] + wv.z * sctx[k + 2] + wv.w * sctx[k + 3];
      }
      total = V[t] * tanhf(inp[b * 512 + t] + bc[t] + acc);
    }
    sred[t] = total;
    __syncthreads();
    for (int s2 = 512; s2 > 0; s2 >>= 1) {
      if (t < s2) sred[t] += sred[t + s2];
      __syncthreads();
    }
    if (t == 0) sexact[i] = sred[0];
  }
  __syncthreads();
  if (t == 0) {
    float dd = den, best = -1e30f;
    int bj = 0x7fffffff;
    for (int i = 0; i < n; ++i) {
      float e = sexact[i];
      int j = scand_j[i];
      dd += expf(10.f * tanhf(e) - Lref) - expf(10.f * tanhf(scand_a[i]) - Lref);
      if (e > best || (e == best && j < bj)) { best = e; bj = j; }
    }
    out[b] = (float)bj;
    out[32 + b] = expf(10.f * tanhf(best) - Lref) / dd;
  }
}

extern "C" void kernel_launch(void* const* d_in, const int* in_sizes, int n_in,
                              void* d_out, int out_size, void* d_ws, size_t ws_size,
                              hipStream_t stream) {
  const float* x    = (const float*)d_in[0];
  const float* ctx  = (const float*)d_in[1];
  const unsigned char* mask = (const unsigned char*)d_in[2];
  const float* Wi   = (const float*)d_in[3];
  const float* bi   = (const float*)d_in[4];
  const float* Wc0  = (const float*)d_in[5];
  const float* bc0  = (const float*)d_in[6];
  const float* Wc1  = (const float*)d_in[7];
  const float* bc1  = (const float*)d_in[8];
  const float* Wc2  = (const float*)d_in[9];
  const float* bc2  = (const float*)d_in[10];
  const float* Wc3  = (const float*)d_in[11];
  const float* bc3  = (const float*)d_in[12];
  const float* V    = (const float*)d_in[13];
  float* out = (float*)d_out;

  float* inp = (float*)d_ws;             // 16384 f32
  float* att = inp + 16384;              // 262144 f32
  short* Whi = (short*)(att + 262144);   // 1048576 shorts (2 MB)

  hipMemsetAsync(att, 0, 262144 * sizeof(float), stream);
  prep_small_k<<<576, 256, 0, stream>>>(x, Wi, bi, Wc0, Wc1, Wc2, Wc3, Whi, inp);
  gemm_att_k<<<dim3(8, 256), 1024, 0, stream>>>(ctx, Whi,
      inp, bc0, bc1, bc2, bc3, V, att);
  tail_k<<<32, 1024, 0, stream>>>(att, mask, ctx, Wc0, Wc1, Wc2, Wc3,
      bc0, bc1, bc2, bc3, inp, V, out);
}

// Round 19
// 267.858 us; speedup vs baseline: 1.2673x; 1.0884x over previous
//
#include <hip/hip_runtime.h>
#include <math.h>

typedef __bf16 bf16x8 __attribute__((ext_vector_type(8)));
typedef float f32x4 __attribute__((ext_vector_type(4)));
typedef short short8v __attribute__((ext_vector_type(8)));

#define MARGIN 0.01f
#define NCAND 32

#define WAITL  do { asm volatile("s_waitcnt lgkmcnt(0)" ::: "memory"); __builtin_amdgcn_sched_barrier(0); } while (0)
#define WAITV0 do { asm volatile("s_waitcnt vmcnt(0)" ::: "memory"); __builtin_amdgcn_sched_barrier(0); } while (0)
#define BARR   do { __builtin_amdgcn_s_barrier(); __builtin_amdgcn_sched_barrier(0); } while (0)

__device__ __forceinline__ unsigned short f2bf(float f) {
  unsigned u = __float_as_uint(f);
  u += 0x7fffu + ((u >> 16) & 1u);
  return (unsigned short)(u >> 16);
}
__device__ __forceinline__ float tanh_fast(float x) {
  float e = __builtin_amdgcn_exp2f(x * 2.885390081777927f);
  return 1.f - 2.f * __builtin_amdgcn_rcpf(e + 1.f);
}
__device__ __forceinline__ float exp_fast(float x) {
  return __builtin_amdgcn_exp2f(x * 1.4426950408889634f);
}
__device__ __forceinline__ void gl_lds16(const void* g, void* l) {
  __builtin_amdgcn_global_load_lds(
      (const __attribute__((address_space(1))) unsigned int*)g,
      (__attribute__((address_space(3))) unsigned int*)l, 16, 0, 0);
}
// pack 2 fp32 -> 2 bf16, 1 instruction
__device__ __forceinline__ int cvt_pk_bf16(float lo, float hi) {
  int r;
  asm("v_cvt_pk_bf16_f32 %0, %1, %2" : "=v"(r) : "v"(lo), "v"(hi));
  return r;
}
// DPP row_shr 16-lane reduce; row sum lands in lane 15 (verified R11).
__device__ __forceinline__ float dpp_row_reduce(float v) {
  int x;
  x = __builtin_amdgcn_update_dpp(0, __builtin_bit_cast(int, v), 0x118, 0xf, 0xf, true);
  v += __builtin_bit_cast(float, x);
  x = __builtin_amdgcn_update_dpp(0, __builtin_bit_cast(int, v), 0x114, 0xf, 0xf, true);
  v += __builtin_bit_cast(float, x);
  x = __builtin_amdgcn_update_dpp(0, __builtin_bit_cast(int, v), 0x112, 0xf, 0xf, true);
  v += __builtin_bit_cast(float, x);
  x = __builtin_amdgcn_update_dpp(0, __builtin_bit_cast(int, v), 0x111, 0xf, 0xf, true);
  v += __builtin_bit_cast(float, x);
  return v;
}

// Small prep: blocks [0,512) pack W -> Whi regions (TN 0..3, KS 0..15) of
// 512 rows x 32 k bf16; blocks [512,576) inp.
__global__ __launch_bounds__(256) void prep_small_k(
    const float* __restrict__ x, const float* __restrict__ Wi,
    const float* __restrict__ bi,
    const float* __restrict__ w0, const float* __restrict__ w1,
    const float* __restrict__ w2, const float* __restrict__ w3,
    short* __restrict__ Whi, float* __restrict__ inp) {
  int bid = blockIdx.x;
  if (bid < 512) {
    int gid = bid * 256 + threadIdx.x;   // 131072 chunks of 8
    int c = gid & 3, row = (gid >> 2) & 511, TK = gid >> 11;  // TK = TN*16+KS
    int TN = TK >> 4, KS = TK & 15;
    const float* w = (TN == 0) ? w0 : (TN == 1) ? w1 : (TN == 2) ? w2 : w3;
    const float* src = w + (size_t)row * 512 + KS * 32 + c * 8;
    float f[8];
    *(float4*)&f[0] = *(const float4*)(src);
    *(float4*)&f[4] = *(const float4*)(src + 4);
    short8v hv;
    #pragma unroll
    for (int i = 0; i < 8; ++i) hv[i] = (short)f2bf(f[i]);
    *(short8v*)(Whi + (size_t)gid * 8) = hv;
  } else {
    int gid = (bid - 512) * 256 + threadIdx.x;   // 16384
    int b = gid >> 9, h = gid & 511;
    const float* xr = x + b * 512;
    const float* wr = Wi + h * 512;
    float acc = bi[h];
    #pragma unroll 4
    for (int k = 0; k < 512; k += 4) {
      float4 xv = *(const float4*)(xr + k);
      float4 wv = *(const float4*)(wr + k);
      acc += xv.x * wv.x + xv.y * wv.y + xv.z * wv.z + xv.w * wv.w;
    }
    inp[gid] = acc;
  }
}

// GEMM, BN=512, A direct from fp32 ctx with STAGE-TIME bf16 conversion (T14):
// 128x512 tile, 16 K-tiles BK=32, 16 waves (2wr x 8wc), per-wave 64x64.
// Per tile t: issue A(t+2)->regs + B(t+2) gl_lds BEFORE MFMA; after MFMA
// vmcnt(0) + cvt_pk + ds_write_b64 into slot (t+2)%3 (2-barrier slack).
// 3-slot ring (A bf16 8KB + B 32KB = 40KB/slot, 120KB).
__global__ __launch_bounds__(1024, 4) void gemm_att_k(
    const float* __restrict__ ctx, const short* __restrict__ Whi,
    const float* __restrict__ inp,
    const float* __restrict__ bc0, const float* __restrict__ bc1,
    const float* __restrict__ bc2, const float* __restrict__ bc3,
    const float* __restrict__ V, float* __restrict__ att) {
  __shared__ __align__(16) char smem[3][40960];   // [slot][A bf16 8K | B bf16 32K]

  const int t = threadIdx.x;
  int d = blockIdx.x + (blockIdx.y << 3);
  int work = (d & 7) * 256 + (d >> 3);           // XCD-contiguous chunks
  int mt = work >> 2, nt = work & 3;             // 4 nt-blocks share mt's A (L2)
  int b = mt >> 4;
  const float* bc = (nt == 0) ? bc0 : (nt == 1) ? bc1 : (nt == 2) ? bc2 : bc3;

  // A staging coords: thread t -> chunk c=t>>1 (of 512), half h=t&1.
  // row r=c>>2, 16B-chunk q=c&3. fp32 float4 -> 4 bf16 (8B ds_write_b64).
  const int ac = t >> 1, ah = t & 1;
  const int ar = ac >> 2, aq = ac & 3;
  const float* aSrc = ctx + ((size_t)mt * 128 + ar) * 512 + aq * 8 + ah * 4;
  const int aDstOff = ar * 32 + aq * 8 + ah * 4;         // shorts

  auto loadA = [&](int tile) -> float4 { return *(const float4*)(aSrc + tile * 32); };
  auto writeA = [&](const float4& v, int slot) {
    int2 w;
    w.x = cvt_pk_bf16(v.x, v.y);
    w.y = cvt_pk_bf16(v.z, v.w);
    *(int2*)((short*)&smem[slot][0] + aDstOff) = w;
  };
  auto stageB = [&](int tile, int slot) {
    const short* gB = Whi + (((size_t)nt * 16 + tile) << 14) + t * 8;
    short* lB = (short*)&smem[slot][8192] + t * 8;
    gl_lds16(gB,        lB);
    gl_lds16(gB + 8192, lB + 8192);
  };

  f32x4 acc[4][4];
  #pragma unroll
  for (int i = 0; i < 4; ++i)
    #pragma unroll
    for (int j = 0; j < 4; ++j) acc[i][j] = (f32x4){0.f, 0.f, 0.f, 0.f};

  const int lane = t & 63, wid = t >> 6;         // 16 waves
  const int wr = wid >> 3, wc = wid & 7;         // 2 x 8
  const int fr = lane & 15, fq = lane >> 4;
  const int abase = (wr * 64 + fr) * 32 + fq * 8;          // shorts, 128-row A
  const int bbase = 8192 / 2 + (wc * 64 + fr) * 32 + fq * 8;  // shorts from slot base

  // prologue: tiles 0,1
  {
    float4 a0 = loadA(0), a1 = loadA(1);
    stageB(0, 0); stageB(1, 1);
    WAITV0;
    writeA(a0, 0); writeA(a1, 1);
    WAITL;
  }
  BARR;

  #pragma unroll
  for (int tt = 0; tt < 16; ++tt) {
    const int slot = tt % 3;
    const short* As = (const short*)&smem[slot][0];
    float4 anext;
    if (tt < 14) { anext = loadA(tt + 2); stageB(tt + 2, (tt + 2) % 3); }
    bf16x8 a[4], bv[4];
    #pragma unroll
    for (int mi = 0; mi < 4; ++mi) a[mi] = *(const bf16x8*)(As + abase + mi * 512);
    #pragma unroll
    for (int ni = 0; ni < 4; ++ni) bv[ni] = *(const bf16x8*)(As + bbase + ni * 512);
    WAITL;
    __builtin_amdgcn_s_setprio(1);
    #pragma unroll
    for (int mi = 0; mi < 4; ++mi)
      #pragma unroll
      for (int ni = 0; ni < 4; ++ni)
        acc[mi][ni] = __builtin_amdgcn_mfma_f32_16x16x32_bf16(a[mi], bv[ni], acc[mi][ni], 0, 0, 0);
    __builtin_amdgcn_s_setprio(0);
    __builtin_amdgcn_sched_barrier(0);
    if (tt < 14) {
      WAITV0;                        // anext + B(t+2) landed under MFMA
      writeA(anext, (tt + 2) % 3);   // write-late; drained by next tile's WAITL
    }
    BARR;
  }

  // epilogue: att[b, nt*2048 + s] += this wave's 64-col partial
  float vV[4], vP[4];
  #pragma unroll
  for (int ni = 0; ni < 4; ++ni) {
    int j = wc * 64 + ni * 16 + fr;
    vV[ni] = V[j];
    vP[ni] = inp[b * 512 + j] + bc[j];
  }
  size_t abatt = (size_t)b * 8192 + (size_t)nt * 2048;
  #pragma unroll
  for (int mi = 0; mi < 4; ++mi) {
    #pragma unroll
    for (int r = 0; r < 4; ++r) {
      float sum = 0.f;
      #pragma unroll
      for (int ni = 0; ni < 4; ++ni)
        sum += vV[ni] * tanh_fast(vP[ni] + acc[mi][ni][r]);
      sum = dpp_row_reduce(sum);
      if (fr == 15) {
        int s2 = (mt & 15) * 128 + wr * 64 + mi * 16 + fq * 4 + r;
        atomicAdd(&att[abatt + s2], sum);
      }
    }
  }
}

// Tail (fast-math): max + denom + candidates, fp32 rescore, final outputs.
__global__ __launch_bounds__(1024) void tail_k(const float* __restrict__ att,
    const unsigned char* __restrict__ mask, const float* __restrict__ ctx,
    const float* __restrict__ Wc0, const float* __restrict__ Wc1,
    const float* __restrict__ Wc2, const float* __restrict__ Wc3,
    const float* __restrict__ bc0, const float* __restrict__ bc1,
    const float* __restrict__ bc2, const float* __restrict__ bc3,
    const float* __restrict__ inp, const float* __restrict__ V,
    float* __restrict__ out) {
  int b = blockIdx.x, t = threadIdx.x;
  __shared__ float sred[1024];
  __shared__ float sctx[512];
  __shared__ int scnt;
  __shared__ int scand_j[NCAND];
  __shared__ float scand_a[NCAND];
  __shared__ float sexact[NCAND];

  if (t == 0) scnt = 0;
  float bm = -1e30f;
  for (int j = t; j < 8192; j += 1024) {
    if (mask[b * 2048 + (j & 2047)]) continue;
    bm = fmaxf(bm, att[(size_t)b * 8192 + j]);
  }
  sred[t] = bm;
  __syncthreads();
  for (int s2 = 512; s2 > 0; s2 >>= 1) {
    if (t < s2) sred[t] = fmaxf(sred[t], sred[t + s2]);
    __syncthreads();
  }
  float mx = sred[0];
  float Lref = 10.f * tanh_fast(mx);
  __syncthreads();
  float se = 0.f;
  for (int j = t; j < 8192; j += 1024) {
    if (mask[b * 2048 + (j & 2047)]) continue;
    float a = att[(size_t)b * 8192 + j];
    se += exp_fast(10.f * tanh_fast(a) - Lref);
    if (a >= mx - MARGIN) {
      int slot = atomicAdd(&scnt, 1);
      if (slot < NCAND) { scand_j[slot] = j; scand_a[slot] = a; }
    }
  }
  sred[t] = se;
  __syncthreads();
  for (int s2 = 512; s2 > 0; s2 >>= 1) {
    if (t < s2) sred[t] += sred[t + s2];
    __syncthreads();
  }
  float den = sred[0];
  int n = min(scnt, NCAND);
  for (int j = t; j < 2048; j += 1024)
    out[64 + b * 2048 + j] = mask[b * 2048 + j] ? 1.0f : 0.0f;
  for (int i = 0; i < n; ++i) {
    int jj = scand_j[i];
    int g = jj >> 11, s = jj & 2047;
    const float* W  = (g == 0) ? Wc0 : (g == 1) ? Wc1 : (g == 2) ? Wc2 : Wc3;
    const float* bc = (g == 0) ? bc0 : (g == 1) ? bc1 : (g == 2) ? bc2 : bc3;
    const float* cr = ctx + ((size_t)b * 2048 + s) * 512;
    __syncthreads();
    if (t < 512) sctx[t] = cr[t];
    __syncthreads();
    float total = 0.f;
    if (t < 512) {
      const float* wrp = W + (size_t)t * 512;
      float acc = 0.f;
      #pragma unroll 4
      for (int k = 0; k < 512; k += 4) {
        float4 wv = *(const float4*)(wrp + k);
        acc += wv.x * sctx[k] + wv.y * sctx[k + 1] + wv.z * sctx[k + 2] + wv.w * sctx[k + 3];
      }
      total = V[t] * tanhf(inp[b * 512 + t] + bc[t] + acc);
    }
    sred[t] = total;
    __syncthreads();
    for (int s2 = 512; s2 > 0; s2 >>= 1) {
      if (t < s2) sred[t] += sred[t + s2];
      __syncthreads();
    }
    if (t == 0) sexact[i] = sred[0];
  }
  __syncthreads();
  if (t == 0) {
    float dd = den, best = -1e30f;
    int bj = 0x7fffffff;
    for (int i = 0; i < n; ++i) {
      float e = sexact[i];
      int j = scand_j[i];
      dd += exp_fast(10.f * tanh_fast(e) - Lref) - exp_fast(10.f * tanh_fast(scand_a[i]) - Lref);
      if (e > best || (e == best && j < bj)) { best = e; bj = j; }
    }
    out[b] = (float)bj;
    out[32 + b] = exp_fast(10.f * tanh_fast(best) - Lref) / dd;
  }
}

extern "C" void kernel_launch(void* const* d_in, const int* in_sizes, int n_in,
                              void* d_out, int out_size, void* d_ws, size_t ws_size,
                              hipStream_t stream) {
  const float* x    = (const float*)d_in[0];
  const float* ctx  = (const float*)d_in[1];
  const unsigned char* mask = (const unsigned char*)d_in[2];
  const float* Wi   = (const float*)d_in[3];
  const float* bi   = (const float*)d_in[4];
  const float* Wc0  = (const float*)d_in[5];
  const float* bc0  = (const float*)d_in[6];
  const float* Wc1  = (const float*)d_in[7];
  const float* bc1  = (const float*)d_in[8];
  const float* Wc2  = (const float*)d_in[9];
  const float* bc2  = (const float*)d_in[10];
  const float* Wc3  = (const float*)d_in[11];
  const float* bc3  = (const float*)d_in[12];
  const float* V    = (const float*)d_in[13];
  float* out = (float*)d_out;

  float* inp = (float*)d_ws;             // 16384 f32
  float* att = inp + 16384;              // 262144 f32
  short* Whi = (short*)(att + 262144);   // 1048576 shorts (2 MB)

  hipMemsetAsync(att, 0, 262144 * sizeof(float), stream);
  prep_small_k<<<576, 256, 0, stream>>>(x, Wi, bi, Wc0, Wc1, Wc2, Wc3, Whi, inp);
  gemm_att_k<<<dim3(8, 256), 1024, 0, stream>>>(ctx, Whi,
      inp, bc0, bc1, bc2, bc3, V, att);
  tail_k<<<32, 1024, 0, stream>>>(att, mask, ctx, Wc0, Wc1, Wc2, Wc3,
      bc0, bc1, bc2, bc3, inp, V, out);
}